// Round 16
// baseline (103.345 us; speedup 1.0000x reference)
//
#include <hip/hip_runtime.h>
#include <hip/hip_bf16.h>
#include <stdint.h>

// Problem constants
#define NROWS 8192
#define FDIM 256
#define MCOLS 20000
#define NT32 625           // 20000 / 32, exact -> no tail masking
#define MSPLIT 16
#define NCLS 1000
#define LOG2E 1.44269504088896f
#define LN2   0.69314718055994f

// ws layout (bytes), total ~15.5 MB:
//   Mb2  bf16 memory, MFMA-fragment order : [0, 10240000)
//   Fb   bf16 box*5*log2e (row-major)     : [10240000, 14434304)
//   wsel weighted sel logits              : [14434304, 14467072)
//   pm   partial max [16][N]              : [14467072, 14991360)
//   ps   partial sum [16][N]              : [14991360, 15515648)
//   bpart block partials                  : [15515648, 15515776)

typedef short short8 __attribute__((ext_vector_type(8)));
typedef float f32x16 __attribute__((ext_vector_type(16)));

typedef __attribute__((address_space(3))) unsigned int lds_u32;
typedef const __attribute__((address_space(1))) unsigned int glb_u32;

__device__ __forceinline__ float ex2(float x) {   // raw v_exp_f32 (2^x), no ocml wrapper
    float r;
    asm("v_exp_f32 %0, %1" : "=v"(r) : "v"(x));
    return r;
}

__device__ __forceinline__ unsigned short f2bf(float x) {
    unsigned u = __float_as_uint(x);
    unsigned r = (u + 0x7FFFu + ((u >> 16) & 1u)) >> 16;   // RNE
    return (unsigned short)r;
}

// max of 16-vector via 3-ary nesting (clang can fuse to v_max3_f32)
__device__ __forceinline__ float vmax16(f32x16 v) {
    float x0 = fmaxf(fmaxf(v[0],  v[1]),  v[2]);
    float x1 = fmaxf(fmaxf(v[3],  v[4]),  v[5]);
    float x2 = fmaxf(fmaxf(v[6],  v[7]),  v[8]);
    float x3 = fmaxf(fmaxf(v[9],  v[10]), v[11]);
    float x4 = fmaxf(fmaxf(v[12], v[13]), v[14]);
    float x5 = fmaxf(fmaxf(x0, x1), x2);
    float x6 = fmaxf(fmaxf(x3, x4), v[15]);
    return fmaxf(x5, x6);
}

// Fused prep: blocks [0,2500) build Mb2 (fragment-order bf16 memory);
// blocks [2500,4548) build Fb (row-major bf16 box * 5*log2e).
__global__ void prep_kernel(const float* __restrict__ Mem, unsigned short* __restrict__ Mb2,
                            const float* __restrict__ F, unsigned short* __restrict__ Fb) {
    int b = blockIdx.x;
    if (b < 2500) {
        // Mb2: granule g = (t*16 + kk)*64 + s holds Mem[t*32 + (s&31)][kk*16 + (s>>5)*8 ..+8]
        int g = b * 256 + threadIdx.x;
        int s = g & 63, kk = (g >> 6) & 15, t = g >> 10;
        const float* src = Mem + (size_t)(t * 32 + (s & 31)) * FDIM + kk * 16 + (s >> 5) * 8;
        float4 v0 = ((const float4*)src)[0];
        float4 v1 = ((const float4*)src)[1];
        short8 w;
        w[0] = (short)f2bf(v0.x); w[1] = (short)f2bf(v0.y);
        w[2] = (short)f2bf(v0.z); w[3] = (short)f2bf(v0.w);
        w[4] = (short)f2bf(v1.x); w[5] = (short)f2bf(v1.y);
        w[6] = (short)f2bf(v1.z); w[7] = (short)f2bf(v1.w);
        *(short8*)(Mb2 + (size_t)g * 8) = w;
    } else {
        int idx = (b - 2500) * 256 + threadIdx.x;   // 2048 blocks x 256 = 524288 float4s
        float4 v = ((const float4*)F)[idx];
        const float sc = 5.0f * LOG2E;
        ushort4 o;
        o.x = f2bf(v.x * sc); o.y = f2bf(v.y * sc);
        o.z = f2bf(v.z * sc); o.w = f2bf(v.w * sc);
        ((ushort4*)Fb)[idx] = o;
    }
}

// Selected logits: wsel[i] = 5 * sum_d d * dot(F[i], Mem[trace[label_i][d]]), fp32-exact,
// natural-log domain (independent of the exp2 trick in lse_gemm).
__global__ void sel_kernel(const int* __restrict__ gt, const float* __restrict__ F,
                           const float* __restrict__ Mem, const int* __restrict__ trace,
                           float* __restrict__ wsel) {
    int lane = threadIdx.x & 63, wid = threadIdx.x >> 6;
    int i = blockIdx.x * 4 + wid;
    int label = gt[i];
    float w = 0.0f;
    if (label >= 0 && label < NCLS) {
        float4 fv = ((const float4*)(F + (size_t)i * FDIM))[lane];
        #pragma unroll
        for (int d = 1; d <= 3; ++d) {
            int tr = trace[label * 4 + d];
            float4 mv = ((const float4*)(Mem + (size_t)tr * FDIM))[lane];
            float dot = fv.x*mv.x + fv.y*mv.y + fv.z*mv.z + fv.w*mv.w;
            #pragma unroll
            for (int off = 32; off >= 1; off >>= 1) dot += __shfl_xor(dot, off, 64);
            w += (float)d * dot;
        }
    }
    if (lane == 0) wsel[i] = w * 5.0f;   // 1/T
}

// Fused GEMM + online log2-sum-exp2 partials -- swapped-operand 32x32x16 on
// fragment-ordered Mb2, 64 rows/wave (R15), now with 2-TILE MACRO-BUFFERS:
// stage 32KB (2 tiles) per sync period, compute both subtiles, ONE barrier.
// Barrier count 39 -> 20; the implicit vmcnt drain at each barrier covers
// loads issued a full macro (~5000 cyc) earlier. LDS 2x32KB = 64KB/block --
// free capacity since residency is register-bound at 2 blocks/CU (128<=160KB).
__global__ __launch_bounds__(256, 2) void lse_gemm(
        const unsigned short* __restrict__ Fb, const unsigned short* __restrict__ Mb2,
        float* __restrict__ pm, float* __restrict__ ps) {
    __shared__ __align__(16) char smem[2 * 32768];  // 2 macro-buffers x 2 tiles

    const int split  = blockIdx.x;   // 0..15
    const int rowblk = blockIdx.y;   // 0..31
    const int tid  = threadIdx.x;
    const int lane = tid & 63, wid = tid >> 6;
    const int r0 = lane & 31;        // A-row within the 32-row half AND B-col
    const int hi = lane >> 5;        // k-slice half
    const int rowbase = rowblk * 256 + wid * 64;
    const int l16 = lane << 4;       // lane byte offset within a fragment

    // A fragments (Y-operand), two row-halves (al: +r0, ah: +32+r0)
    short8 al[16], ah[16];
    #pragma unroll
    for (int kk = 0; kk < 16; ++kk) {
        al[kk] = *(const short8*)(Fb + (size_t)(rowbase + r0)      * FDIM + kk * 16 + hi * 8);
        ah[kk] = *(const short8*)(Fb + (size_t)(rowbase + 32 + r0) * FDIM + kk * 16 + hi * 8);
    }

    // scalar online state: one row per lane, per half
    float m0 = -3.0e38f, s0 = 0.0f, m1 = -3.0e38f, s1 = 0.0f;

    const int t0 = (split * NT32) / MSPLIT;
    const int t1 = ((split + 1) * NT32) / MSPLIT;   // 39-40 tiles per split
    const int nt = t1 - t0, nmac = nt >> 1, tail = nt & 1;

    // STAGE2: verbatim linear copy of 32KB (tiles t, t+1); 8 gload_lds/thread.
#define STAGE2(BUF, t)                                                             \
    do {                                                                           \
        const char* srcT = (const char*)Mb2 + (size_t)(t) * 16384 + l16;           \
        _Pragma("unroll")                                                          \
        for (int c = 0; c < 8; ++c) {                                              \
            __builtin_amdgcn_global_load_lds(                                      \
                (glb_u32*)(srcT + (wid * 8 + c) * 1024),                           \
                (lds_u32*)(smem + (BUF) * 32768 + (wid * 8 + c) * 1024),           \
                16, 0, 0);                                                         \
        }                                                                          \
    } while (0)

    // STAGE1: single tile into subtile-0 slot of macro-buffer BUF.
#define STAGE1(BUF, t)                                                             \
    do {                                                                           \
        const char* srcT = (const char*)Mb2 + (size_t)(t) * 16384 + l16;           \
        _Pragma("unroll")                                                          \
        for (int c = 0; c < 4; ++c) {                                              \
            __builtin_amdgcn_global_load_lds(                                      \
                (glb_u32*)(srcT + (wid * 4 + c) * 1024),                           \
                (lds_u32*)(smem + (BUF) * 32768 + (wid * 4 + c) * 1024),           \
                16, 0, 0);                                                         \
        }                                                                          \
    } while (0)

    // SUB: one 32-col subtile at LDS byte base BB: 32 MFMA (2 chains) + softmax.
#define SUB(BB)                                                                    \
    do {                                                                           \
        const char* bp = smem + (BB) + l16;                                        \
        f32x16 accL = {0,0,0,0,0,0,0,0,0,0,0,0,0,0,0,0};                           \
        f32x16 accH = {0,0,0,0,0,0,0,0,0,0,0,0,0,0,0,0};                           \
        __builtin_amdgcn_s_setprio(1);                                             \
        _Pragma("unroll")                                                          \
        for (int kk = 0; kk < 16; ++kk) {                                          \
            short8 b = *(const short8*)(bp + kk * 1024);                           \
            accL = __builtin_amdgcn_mfma_f32_32x32x16_bf16(b, al[kk], accL, 0, 0, 0); \
            accH = __builtin_amdgcn_mfma_f32_32x32x16_bf16(b, ah[kk], accH, 0, 0, 0); \
        }                                                                          \
        __builtin_amdgcn_s_setprio(0);                                             \
        {                                                                          \
            float nm = fmaxf(vmax16(accL), m0);                                    \
            float p0 = 0.f, p1 = 0.f, p2 = 0.f, p3 = 0.f;                          \
            _Pragma("unroll")                                                      \
            for (int i = 0; i < 16; i += 4) {                                      \
                p0 += ex2(accL[i]     - nm); p1 += ex2(accL[i + 1] - nm);          \
                p2 += ex2(accL[i + 2] - nm); p3 += ex2(accL[i + 3] - nm);          \
            }                                                                      \
            s0 = fmaf(s0, ex2(m0 - nm), (p0 + p1) + (p2 + p3));                    \
            m0 = nm;                                                               \
        }                                                                          \
        {                                                                          \
            float nm = fmaxf(vmax16(accH), m1);                                    \
            float p0 = 0.f, p1 = 0.f, p2 = 0.f, p3 = 0.f;                          \
            _Pragma("unroll")                                                      \
            for (int i = 0; i < 16; i += 4) {                                      \
                p0 += ex2(accH[i]     - nm); p1 += ex2(accH[i + 1] - nm);          \
                p2 += ex2(accH[i + 2] - nm); p3 += ex2(accH[i + 3] - nm);          \
            }                                                                      \
            s1 = fmaf(s1, ex2(m1 - nm), (p0 + p1) + (p2 + p3));                    \
            m1 = nm;                                                               \
        }                                                                          \
    } while (0)

    STAGE2(0, t0);     // nt >= 39, first macro always full
    __syncthreads();

    for (int mi = 0; mi < nmac; ++mi) {
        const int bb = (mi & 1) * 32768;
        if (mi + 1 < nmac)      STAGE2((mi & 1) ^ 1, t0 + 2 * mi + 2);
        else if (tail)          STAGE1((mi & 1) ^ 1, t0 + 2 * mi + 2);
        SUB(bb);                // subtile 0 (no barrier between subtiles)
        SUB(bb + 16384);        // subtile 1
        __syncthreads();        // one barrier per 2 tiles
    }
    if (tail) SUB((nmac & 1) * 32768);

#undef SUB
#undef STAGE1
#undef STAGE2

    // Combine the two k-slice halves: lane l and l^32 hold the same row's two
    // 16-col subsets (for both row-halves).
    {
        float om = __shfl_xor(m0, 32, 64);
        float os = __shfl_xor(s0, 32, 64);
        float nm = fmaxf(m0, om);
        float sf = fmaf(s0, ex2(m0 - nm), os * ex2(om - nm));
        if (lane < 32) {
            pm[split * NROWS + rowbase + lane] = nm;
            ps[split * NROWS + rowbase + lane] = sf;
        }
    }
    {
        float om = __shfl_xor(m1, 32, 64);
        float os = __shfl_xor(s1, 32, 64);
        float nm = fmaxf(m1, om);
        float sf = fmaf(s1, ex2(m1 - nm), os * ex2(om - nm));
        if (lane < 32) {
            pm[split * NROWS + rowbase + 32 + lane] = nm;
            ps[split * NROWS + rowbase + 32 + lane] = sf;
        }
    }
}

__global__ void finalize_kernel(const int* __restrict__ gt, const float* __restrict__ wsel,
                                const float* __restrict__ pm, const float* __restrict__ ps,
                                float* __restrict__ bpart) {
    int tid = threadIdx.x;
    int i = blockIdx.x * 256 + tid;
    float mv[MSPLIT];
    float M = -3.0e38f;
    #pragma unroll
    for (int k = 0; k < MSPLIT; ++k) { mv[k] = pm[k * NROWS + i]; M = fmaxf(M, mv[k]); }
    float S = 0.0f;
    #pragma unroll
    for (int k = 0; k < MSPLIT; ++k) S += ps[k * NROWS + i] * ex2(mv[k] - M);
    float lse = (M + __log2f(S)) * LN2;   // back to natural-log domain
    int label = gt[i];
    float per = (label >= 0 && label < NCLS) ? (lse - wsel[i] * (1.0f / 6.0f)) : 0.0f;
    #pragma unroll
    for (int off = 32; off >= 1; off >>= 1) per += __shfl_xor(per, off, 64);
    __shared__ float red[4];
    int lane = tid & 63, wid = tid >> 6;
    if (lane == 0) red[wid] = per;
    __syncthreads();
    if (tid == 0) bpart[blockIdx.x] = red[0] + red[1] + red[2] + red[3];
}

__global__ void sum_kernel(const float* __restrict__ bpart, float* __restrict__ out) {
    int tid = threadIdx.x;
    float v = (tid < 32) ? bpart[tid] : 0.0f;
    #pragma unroll
    for (int off = 32; off >= 1; off >>= 1) v += __shfl_xor(v, off, 64);
    if (tid == 0) out[0] = 0.001f * v;
}

extern "C" void kernel_launch(void* const* d_in, const int* in_sizes, int n_in,
                              void* d_out, int out_size, void* d_ws, size_t ws_size,
                              hipStream_t stream) {
    const int*   gt    = (const int*)d_in[0];
    const float* F     = (const float*)d_in[1];
    const float* Mem   = (const float*)d_in[2];
    const int*   trace = (const int*)d_in[3];
    float* out = (float*)d_out;

    char* w = (char*)d_ws;
    unsigned short* Mb2 = (unsigned short*)w;
    unsigned short* Fb  = (unsigned short*)(w + 10240000);
    float* wsel  = (float*)(w + 14434304);
    float* pm    = (float*)(w + 14467072);
    float* ps    = (float*)(w + 14991360);
    float* bpart = (float*)(w + 15515648);

    prep_kernel<<<dim3(4548), dim3(256), 0, stream>>>(Mem, Mb2, F, Fb);
    sel_kernel<<<dim3(NROWS / 4), dim3(256), 0, stream>>>(gt, F, Mem, trace, wsel);
    lse_gemm<<<dim3(MSPLIT, NROWS / 256), dim3(256), 0, stream>>>(Fb, Mb2, pm, ps);
    finalize_kernel<<<dim3(NROWS / 256), dim3(256), 0, stream>>>(gt, wsel, pm, ps, bpart);
    sum_kernel<<<dim3(1), dim3(64), 0, stream>>>(bpart, out);
}

// Round 17
// 98.679 us; speedup vs baseline: 1.0473x; 1.0473x over previous
//
#include <hip/hip_runtime.h>
#include <hip/hip_bf16.h>
#include <stdint.h>

// Problem constants
#define NROWS 8192
#define FDIM 256
#define MCOLS 20000
#define NT32 625           // 20000 / 32, exact -> no tail masking
#define MSPLIT 8           // grid 8 x 32 = 256 blocks = EXACTLY 1/CU, one generation
#define NCLS 1000
#define LOG2E 1.44269504088896f
#define LN2   0.69314718055994f

// ws layout (bytes), total ~15.5 MB:
//   Mb2  bf16 memory, MFMA-fragment order : [0, 10240000)
//   Fb   bf16 box*5*log2e (row-major)     : [10240000, 14434304)
//   wsel weighted sel logits              : [14434304, 14467072)
//   pm   partial max [8][N]               : [14467072, 14991360)
//   ps   partial sum [8][N]               : [14991360, 15515648)
//   bpart block partials                  : [15515648, 15515776)

typedef short short8 __attribute__((ext_vector_type(8)));
typedef float f32x16 __attribute__((ext_vector_type(16)));

typedef __attribute__((address_space(3))) unsigned int lds_u32;
typedef const __attribute__((address_space(1))) unsigned int glb_u32;

__device__ __forceinline__ float ex2(float x) {   // raw v_exp_f32 (2^x)
    float r;
    asm("v_exp_f32 %0, %1" : "=v"(r) : "v"(x));
    return r;
}

__device__ __forceinline__ unsigned short f2bf(float x) {
    unsigned u = __float_as_uint(x);
    unsigned r = (u + 0x7FFFu + ((u >> 16) & 1u)) >> 16;   // RNE
    return (unsigned short)r;
}

// max of 16-vector via 3-ary nesting (fuses to v_max3_f32)
__device__ __forceinline__ float vmax16(f32x16 v) {
    float x0 = fmaxf(fmaxf(v[0],  v[1]),  v[2]);
    float x1 = fmaxf(fmaxf(v[3],  v[4]),  v[5]);
    float x2 = fmaxf(fmaxf(v[6],  v[7]),  v[8]);
    float x3 = fmaxf(fmaxf(v[9],  v[10]), v[11]);
    float x4 = fmaxf(fmaxf(v[12], v[13]), v[14]);
    float x5 = fmaxf(fmaxf(x0, x1), x2);
    float x6 = fmaxf(fmaxf(x3, x4), v[15]);
    return fmaxf(x5, x6);
}

// Fused prep + sel:
//   blocks [0,2500)    : Mb2 (fragment-order bf16 memory)
//   blocks [2500,4548) : Fb  (row-major bf16 box * 5*log2e)
//   blocks [4548,6596) : sel (weighted trace logits, fp32-exact)
__global__ void prep_kernel(const float* __restrict__ Mem, unsigned short* __restrict__ Mb2,
                            const float* __restrict__ F, unsigned short* __restrict__ Fb,
                            const int* __restrict__ gt, const int* __restrict__ trace,
                            float* __restrict__ wsel) {
    int b = blockIdx.x;
    if (b < 2500) {
        // Mb2: granule g = (t*16 + kk)*64 + s holds Mem[t*32 + (s&31)][kk*16 + (s>>5)*8 ..+8]
        int g = b * 256 + threadIdx.x;
        int s = g & 63, kk = (g >> 6) & 15, t = g >> 10;
        const float* src = Mem + (size_t)(t * 32 + (s & 31)) * FDIM + kk * 16 + (s >> 5) * 8;
        float4 v0 = ((const float4*)src)[0];
        float4 v1 = ((const float4*)src)[1];
        short8 w;
        w[0] = (short)f2bf(v0.x); w[1] = (short)f2bf(v0.y);
        w[2] = (short)f2bf(v0.z); w[3] = (short)f2bf(v0.w);
        w[4] = (short)f2bf(v1.x); w[5] = (short)f2bf(v1.y);
        w[6] = (short)f2bf(v1.z); w[7] = (short)f2bf(v1.w);
        *(short8*)(Mb2 + (size_t)g * 8) = w;
    } else if (b < 4548) {
        int idx = (b - 2500) * 256 + threadIdx.x;   // 2048 x 256 = 524288 float4s
        float4 v = ((const float4*)F)[idx];
        const float sc = 5.0f * LOG2E;
        ushort4 o;
        o.x = f2bf(v.x * sc); o.y = f2bf(v.y * sc);
        o.z = f2bf(v.z * sc); o.w = f2bf(v.w * sc);
        ((ushort4*)Fb)[idx] = o;
    } else {
        int lane = threadIdx.x & 63, wid = threadIdx.x >> 6;
        int i = (b - 4548) * 4 + wid;
        int label = gt[i];
        float w = 0.0f;
        if (label >= 0 && label < NCLS) {
            float4 fv = ((const float4*)(F + (size_t)i * FDIM))[lane];
            #pragma unroll
            for (int d = 1; d <= 3; ++d) {
                int tr = trace[label * 4 + d];
                float4 mv = ((const float4*)(Mem + (size_t)tr * FDIM))[lane];
                float dot = fv.x*mv.x + fv.y*mv.y + fv.z*mv.z + fv.w*mv.w;
                #pragma unroll
                for (int off = 32; off >= 1; off >>= 1) dot += __shfl_xor(dot, off, 64);
                w += (float)d * dot;
            }
        }
        if (lane == 0) wsel[i] = w * 5.0f;   // 1/T
    }
}

// Fused GEMM + online log2-sum-exp2 partials -- swapped-operand 32x32x16,
// 64 rows/wave on fragment-ordered Mb2. ONE WAVE PER SIMD BY DESIGN
// (waves_per_eu(1,1): full 512-reg budget, even 1-block/CU distribution).
// Within-wave software pipeline: double-buffered accumulators (accA/accB);
// the softmax of tile t-1 is interleaved into tile t's MFMA chain in 4
// chunks -- MFMA occupies the matrix pipe only ~1/32 issue slots, so the
// ~600 VALU cyc of softmax hide entirely in the chain's issue bubbles.
// Grid 8 x 32 = 256 blocks = 1/CU, one generation; 78-79 tiles/split.
__global__ __attribute__((amdgpu_flat_work_group_size(256, 256), amdgpu_waves_per_eu(1, 1)))
void lse_gemm(
        const unsigned short* __restrict__ Fb, const unsigned short* __restrict__ Mb2,
        float* __restrict__ pm, float* __restrict__ ps) {
    __shared__ __align__(16) char smem[2 * 16384];  // 32 KiB, double-buffer

    const int split  = blockIdx.x;   // 0..7 == XCD id -> 2.5MB B-chunk L2-resident
    const int rowblk = blockIdx.y;   // 0..31
    const int tid  = threadIdx.x;
    const int lane = tid & 63, wid = tid >> 6;
    const int r0 = lane & 31;        // A-row within the 32-row half AND B-col
    const int hi = lane >> 5;        // k-slice half
    const int rowbase = rowblk * 256 + wid * 64;
    const int l16 = lane << 4;       // lane byte offset within a fragment

    // A fragments (Y-operand), two row-halves (al: +r0, ah: +32+r0)
    short8 al[16], ah[16];
    #pragma unroll
    for (int kk = 0; kk < 16; ++kk) {
        al[kk] = *(const short8*)(Fb + (size_t)(rowbase + r0)      * FDIM + kk * 16 + hi * 8);
        ah[kk] = *(const short8*)(Fb + (size_t)(rowbase + 32 + r0) * FDIM + kk * 16 + hi * 8);
    }

    // online state: one row per lane, per half
    float m0 = -3.0e38f, s0 = 0.0f, m1 = -3.0e38f, s1 = 0.0f;
    // softmax pipeline temps
    float nmL, nmH, q0, q1, q2, q3, r0x, r1x, r2x, r3x;
    // double-buffered accumulators (named, static -- rule #20)
    f32x16 accLA, accHA, accLB, accHB;

    const int t0 = (split * NT32) / MSPLIT;
    const int t1 = ((split + 1) * NT32) / MSPLIT;   // 78-79 tiles per split

    // Staging: verbatim linear copy of the 16KB fragment-ordered tile chunk.
#define STAGE(BUF, t)                                                              \
    do {                                                                           \
        const char* srcT = (const char*)Mb2 + (size_t)(t) * 16384 + l16;           \
        _Pragma("unroll")                                                          \
        for (int c = 0; c < 4; ++c) {                                              \
            __builtin_amdgcn_global_load_lds(                                      \
                (glb_u32*)(srcT + (wid * 4 + c) * 1024),                           \
                (lds_u32*)(smem + (BUF) * 16384 + (wid * 4 + c) * 1024),           \
                16, 0, 0);                                                         \
        }                                                                          \
    } while (0)

#define MFMA_K(BP, CUR, KK)                                                        \
    {                                                                              \
        short8 b_ = *(const short8*)((BP) + (KK) * 1024);                          \
        accL##CUR = __builtin_amdgcn_mfma_f32_32x32x16_bf16(b_, al[KK], accL##CUR, 0, 0, 0); \
        accH##CUR = __builtin_amdgcn_mfma_f32_32x32x16_bf16(b_, ah[KK], accH##CUR, 0, 0, 0); \
    }

#define SM_P0(P)                                                                   \
    nmL = fmaxf(vmax16(accL##P), m0); nmH = fmaxf(vmax16(accH##P), m1);            \
    q0 = q1 = q2 = q3 = 0.f; r0x = r1x = r2x = r3x = 0.f;

#define SM_P1(P)                                                                   \
    q0 += ex2(accL##P[0] - nmL); q1 += ex2(accL##P[1] - nmL);                      \
    q2 += ex2(accL##P[2] - nmL); q3 += ex2(accL##P[3] - nmL);                      \
    q0 += ex2(accL##P[4] - nmL); q1 += ex2(accL##P[5] - nmL);                      \
    q2 += ex2(accL##P[6] - nmL); q3 += ex2(accL##P[7] - nmL);

#define SM_P2(P)                                                                   \
    q0 += ex2(accL##P[8]  - nmL); q1 += ex2(accL##P[9]  - nmL);                    \
    q2 += ex2(accL##P[10] - nmL); q3 += ex2(accL##P[11] - nmL);                    \
    q0 += ex2(accL##P[12] - nmL); q1 += ex2(accL##P[13] - nmL);                    \
    q2 += ex2(accL##P[14] - nmL); q3 += ex2(accL##P[15] - nmL);                    \
    s0 = fmaf(s0, ex2(m0 - nmL), (q0 + q1) + (q2 + q3)); m0 = nmL;

#define SM_P3(P)                                                                   \
    r0x += ex2(accH##P[0]  - nmH); r1x += ex2(accH##P[1]  - nmH);                  \
    r2x += ex2(accH##P[2]  - nmH); r3x += ex2(accH##P[3]  - nmH);                  \
    r0x += ex2(accH##P[4]  - nmH); r1x += ex2(accH##P[5]  - nmH);                  \
    r2x += ex2(accH##P[6]  - nmH); r3x += ex2(accH##P[7]  - nmH);                  \
    r0x += ex2(accH##P[8]  - nmH); r1x += ex2(accH##P[9]  - nmH);                  \
    r2x += ex2(accH##P[10] - nmH); r3x += ex2(accH##P[11] - nmH);                  \
    r0x += ex2(accH##P[12] - nmH); r1x += ex2(accH##P[13] - nmH);                  \
    r2x += ex2(accH##P[14] - nmH); r3x += ex2(accH##P[15] - nmH);                  \
    s1 = fmaf(s1, ex2(m1 - nmH), (r0x + r1x) + (r2x + r3x)); m1 = nmH;

    // MFMA(tile t -> CUR) with SM(tile t-1 = PRV) interleaved in 4 chunks.
#define PIPE(BUF, CUR, PRV)                                                        \
    do {                                                                           \
        const char* bp_ = smem + (BUF) * 16384 + l16;                              \
        f32x16 z_ = {0,0,0,0,0,0,0,0,0,0,0,0,0,0,0,0};                             \
        accL##CUR = z_; accH##CUR = z_;                                            \
        _Pragma("unroll") for (int kk = 0;  kk < 4;  ++kk) MFMA_K(bp_, CUR, kk)    \
        SM_P0(PRV)                                                                 \
        _Pragma("unroll") for (int kk = 4;  kk < 8;  ++kk) MFMA_K(bp_, CUR, kk)    \
        SM_P1(PRV)                                                                 \
        _Pragma("unroll") for (int kk = 8;  kk < 12; ++kk) MFMA_K(bp_, CUR, kk)    \
        SM_P2(PRV)                                                                 \
        _Pragma("unroll") for (int kk = 12; kk < 16; ++kk) MFMA_K(bp_, CUR, kk)    \
        SM_P3(PRV)                                                                 \
    } while (0)

#define MFMA_ONLY(BUF, CUR)                                                        \
    do {                                                                           \
        const char* bp_ = smem + (BUF) * 16384 + l16;                              \
        f32x16 z_ = {0,0,0,0,0,0,0,0,0,0,0,0,0,0,0,0};                             \
        accL##CUR = z_; accH##CUR = z_;                                            \
        _Pragma("unroll") for (int kk = 0; kk < 16; ++kk) MFMA_K(bp_, CUR, kk)     \
    } while (0)

#define SM_FULL(P) do { SM_P0(P) SM_P1(P) SM_P2(P) SM_P3(P) } while (0)

    // Prologue: tile t0 -> accA (no previous softmax); prefetch t0+1.
    STAGE(0, t0);
    __syncthreads();
    STAGE(1, t0 + 1);          // nt >= 78, always exists
    MFMA_ONLY(0, A);
    __syncthreads();           // buf1 resident; buf0 free

    int t = t0 + 1;
    while (t + 2 <= t1) {
        STAGE(0, t + 1);
        PIPE(1, B, A);         // tile t -> accB, softmax of tile t-1 (accA)
        __syncthreads();
        if (t + 2 < t1) STAGE(1, t + 2);
        PIPE(0, A, B);         // tile t+1 -> accA, softmax of tile t (accB)
        __syncthreads();
        t += 2;
    }
    if (t < t1) {              // one tile left; (t-t0) odd -> buf1 (staged in-loop)
        PIPE(1, B, A);
        SM_FULL(B);
    } else {
        SM_FULL(A);
    }

#undef SM_FULL
#undef MFMA_ONLY
#undef PIPE
#undef SM_P3
#undef SM_P2
#undef SM_P1
#undef SM_P0
#undef MFMA_K
#undef STAGE

    // Combine the two k-slice halves: lane l and l^32 hold the same row's two
    // 16-col subsets (for both row-halves).
    {
        float om = __shfl_xor(m0, 32, 64);
        float os = __shfl_xor(s0, 32, 64);
        float nm = fmaxf(m0, om);
        float sf = fmaf(s0, ex2(m0 - nm), os * ex2(om - nm));
        if (lane < 32) {
            pm[split * NROWS + rowbase + lane] = nm;
            ps[split * NROWS + rowbase + lane] = sf;
        }
    }
    {
        float om = __shfl_xor(m1, 32, 64);
        float os = __shfl_xor(s1, 32, 64);
        float nm = fmaxf(m1, om);
        float sf = fmaf(s1, ex2(m1 - nm), os * ex2(om - nm));
        if (lane < 32) {
            pm[split * NROWS + rowbase + 32 + lane] = nm;
            ps[split * NROWS + rowbase + 32 + lane] = sf;
        }
    }
}

__global__ void finalize_kernel(const int* __restrict__ gt, const float* __restrict__ wsel,
                                const float* __restrict__ pm, const float* __restrict__ ps,
                                float* __restrict__ bpart) {
    int tid = threadIdx.x;
    int i = blockIdx.x * 256 + tid;
    float mv[MSPLIT];
    float M = -3.0e38f;
    #pragma unroll
    for (int k = 0; k < MSPLIT; ++k) { mv[k] = pm[k * NROWS + i]; M = fmaxf(M, mv[k]); }
    float S = 0.0f;
    #pragma unroll
    for (int k = 0; k < MSPLIT; ++k) S += ps[k * NROWS + i] * ex2(mv[k] - M);
    float lse = (M + __log2f(S)) * LN2;   // back to natural-log domain
    int label = gt[i];
    float per = (label >= 0 && label < NCLS) ? (lse - wsel[i] * (1.0f / 6.0f)) : 0.0f;
    #pragma unroll
    for (int off = 32; off >= 1; off >>= 1) per += __shfl_xor(per, off, 64);
    __shared__ float red[4];
    int lane = tid & 63, wid = tid >> 6;
    if (lane == 0) red[wid] = per;
    __syncthreads();
    if (tid == 0) bpart[blockIdx.x] = red[0] + red[1] + red[2] + red[3];
}

__global__ void sum_kernel(const float* __restrict__ bpart, float* __restrict__ out) {
    int tid = threadIdx.x;
    float v = (tid < 32) ? bpart[tid] : 0.0f;
    #pragma unroll
    for (int off = 32; off >= 1; off >>= 1) v += __shfl_xor(v, off, 64);
    if (tid == 0) out[0] = 0.001f * v;
}

extern "C" void kernel_launch(void* const* d_in, const int* in_sizes, int n_in,
                              void* d_out, int out_size, void* d_ws, size_t ws_size,
                              hipStream_t stream) {
    const int*   gt    = (const int*)d_in[0];
    const float* F     = (const float*)d_in[1];
    const float* Mem   = (const float*)d_in[2];
    const int*   trace = (const int*)d_in[3];
    float* out = (float*)d_out;

    char* w = (char*)d_ws;
    unsigned short* Mb2 = (unsigned short*)w;
    unsigned short* Fb  = (unsigned short*)(w + 10240000);
    float* wsel  = (float*)(w + 14434304);
    float* pm    = (float*)(w + 14467072);
    float* ps    = (float*)(w + 14991360);
    float* bpart = (float*)(w + 15515648);

    prep_kernel<<<dim3(6596), dim3(256), 0, stream>>>(Mem, Mb2, F, Fb, gt, trace, wsel);
    lse_gemm<<<dim3(MSPLIT, NROWS / 256), dim3(256), 0, stream>>>(Fb, Mb2, pm, ps);
    finalize_kernel<<<dim3(NROWS / 256), dim3(256), 0, stream>>>(gt, wsel, pm, ps, bpart);
    sum_kernel<<<dim3(1), dim3(64), 0, stream>>>(bpart, out);
}

// Round 18
// 96.864 us; speedup vs baseline: 1.0669x; 1.0187x over previous
//
#include <hip/hip_runtime.h>
#include <hip/hip_bf16.h>
#include <stdint.h>

// Problem constants
#define NROWS 8192
#define FDIM 256
#define MCOLS 20000
#define NT32 625           // 20000 / 32, exact -> no tail masking
#define MSPLIT 8           // grid 8 x 32 = 256 blocks = 1/CU; split == XCD id
#define NCLS 1000
#define LOG2E 1.44269504088896f
#define LN2   0.69314718055994f

// ws layout (bytes), total ~15.5 MB:
//   Mb2  bf16 memory, MFMA-fragment order : [0, 10240000)
//   Fb   bf16 box*5*log2e (row-major)     : [10240000, 14434304)
//   wsel weighted sel logits              : [14434304, 14467072)
//   pm   partial max [8][N]               : [14467072, 14991360)
//   ps   partial sum [8][N]               : [14991360, 15515648)
//   bpart block partials                  : [15515648, 15515776)

typedef short short8 __attribute__((ext_vector_type(8)));
typedef float f32x16 __attribute__((ext_vector_type(16)));

__device__ __forceinline__ float ex2(float x) {   // raw v_exp_f32 (2^x)
    float r;
    asm("v_exp_f32 %0, %1" : "=v"(r) : "v"(x));
    return r;
}

__device__ __forceinline__ unsigned short f2bf(float x) {
    unsigned u = __float_as_uint(x);
    unsigned r = (u + 0x7FFFu + ((u >> 16) & 1u)) >> 16;   // RNE
    return (unsigned short)r;
}

// max of 16-vector via 3-ary nesting (fuses to v_max3_f32)
__device__ __forceinline__ float vmax16(f32x16 v) {
    float x0 = fmaxf(fmaxf(v[0],  v[1]),  v[2]);
    float x1 = fmaxf(fmaxf(v[3],  v[4]),  v[5]);
    float x2 = fmaxf(fmaxf(v[6],  v[7]),  v[8]);
    float x3 = fmaxf(fmaxf(v[9],  v[10]), v[11]);
    float x4 = fmaxf(fmaxf(v[12], v[13]), v[14]);
    float x5 = fmaxf(fmaxf(x0, x1), x2);
    float x6 = fmaxf(fmaxf(x3, x4), v[15]);
    return fmaxf(x5, x6);
}

// Fused prep + sel:
//   blocks [0,2500)    : Mb2 (fragment-order bf16 memory)
//   blocks [2500,4548) : Fb  (row-major bf16 box * 5*log2e)
//   blocks [4548,6596) : sel (weighted trace logits, fp32-exact)
__global__ void prep_kernel(const float* __restrict__ Mem, unsigned short* __restrict__ Mb2,
                            const float* __restrict__ F, unsigned short* __restrict__ Fb,
                            const int* __restrict__ gt, const int* __restrict__ trace,
                            float* __restrict__ wsel) {
    int b = blockIdx.x;
    if (b < 2500) {
        // Mb2: granule g = (t*16 + kk)*64 + s holds Mem[t*32 + (s&31)][kk*16 + (s>>5)*8 ..+8]
        int g = b * 256 + threadIdx.x;
        int s = g & 63, kk = (g >> 6) & 15, t = g >> 10;
        const float* src = Mem + (size_t)(t * 32 + (s & 31)) * FDIM + kk * 16 + (s >> 5) * 8;
        float4 v0 = ((const float4*)src)[0];
        float4 v1 = ((const float4*)src)[1];
        short8 w;
        w[0] = (short)f2bf(v0.x); w[1] = (short)f2bf(v0.y);
        w[2] = (short)f2bf(v0.z); w[3] = (short)f2bf(v0.w);
        w[4] = (short)f2bf(v1.x); w[5] = (short)f2bf(v1.y);
        w[6] = (short)f2bf(v1.z); w[7] = (short)f2bf(v1.w);
        *(short8*)(Mb2 + (size_t)g * 8) = w;
    } else if (b < 4548) {
        int idx = (b - 2500) * 256 + threadIdx.x;   // 2048 x 256 = 524288 float4s
        float4 v = ((const float4*)F)[idx];
        const float sc = 5.0f * LOG2E;
        ushort4 o;
        o.x = f2bf(v.x * sc); o.y = f2bf(v.y * sc);
        o.z = f2bf(v.z * sc); o.w = f2bf(v.w * sc);
        ((ushort4*)Fb)[idx] = o;
    } else {
        int lane = threadIdx.x & 63, wid = threadIdx.x >> 6;
        int i = (b - 4548) * 4 + wid;
        int label = gt[i];
        float w = 0.0f;
        if (label >= 0 && label < NCLS) {
            float4 fv = ((const float4*)(F + (size_t)i * FDIM))[lane];
            #pragma unroll
            for (int d = 1; d <= 3; ++d) {
                int tr = trace[label * 4 + d];
                float4 mv = ((const float4*)(Mem + (size_t)tr * FDIM))[lane];
                float dot = fv.x*mv.x + fv.y*mv.y + fv.z*mv.z + fv.w*mv.w;
                #pragma unroll
                for (int off = 32; off >= 1; off >>= 1) dot += __shfl_xor(dot, off, 64);
                w += (float)d * dot;
            }
        }
        if (lane == 0) wsel[i] = w * 5.0f;   // 1/T
    }
}

// Fused GEMM + online log2-sum-exp2 partials -- swapped-operand 32x32x16,
// 64 rows/wave, NO LDS / NO BARRIERS: fragment-ordered Mb2 lets each wave
// global_load_dwordx4 its exact B-fragments (1KB contiguous per fragment,
// coalesced; 4 waves/CU read the same tile -> ~3/4 L1 hits; per-XCD 2.5MB
// chunk L2-resident). B double-buffered in registers (b0/b1, static unroll),
// loads issued a FULL TILE ahead in source -> latency covered regardless of
// scheduler mood. Softmax of tile t-1 interleaved into tile t's MFMA chain.
// waves_per_eu(1,1): full 512-reg budget (B 128 VGPR + al/ah/acc ~192 AGPR).
__global__ __attribute__((amdgpu_flat_work_group_size(256, 256), amdgpu_waves_per_eu(1, 1)))
void lse_gemm(
        const unsigned short* __restrict__ Fb, const unsigned short* __restrict__ Mb2,
        float* __restrict__ pm, float* __restrict__ ps) {
    const int split  = blockIdx.x;   // 0..7 == XCD id (dispatch id % 8)
    const int rowblk = blockIdx.y;   // 0..31
    const int tid  = threadIdx.x;
    const int lane = tid & 63, wid = tid >> 6;
    const int r0 = lane & 31;        // A-row within the 32-row half AND B-col
    const int hi = lane >> 5;        // k-slice half
    const int rowbase = rowblk * 256 + wid * 64;
    const int l16 = lane << 4;       // lane byte offset within a fragment

    // A fragments (Y-operand), two row-halves (al: +r0, ah: +32+r0)
    short8 al[16], ah[16];
    #pragma unroll
    for (int kk = 0; kk < 16; ++kk) {
        al[kk] = *(const short8*)(Fb + (size_t)(rowbase + r0)      * FDIM + kk * 16 + hi * 8);
        ah[kk] = *(const short8*)(Fb + (size_t)(rowbase + 32 + r0) * FDIM + kk * 16 + hi * 8);
    }

    // online state: one row per lane, per half
    float m0 = -3.0e38f, s0 = 0.0f, m1 = -3.0e38f, s1 = 0.0f;
    // softmax pipeline temps
    float nmL, nmH, q0, q1, q2, q3, r0x, r1x, r2x, r3x;
    // double-buffered accumulators + B-fragment register buffers (static idx)
    f32x16 accLA, accHA, accLB, accHB;
    short8 b0[16], b1[16];

    const int t0 = (split * NT32) / MSPLIT;
    const int t1 = ((split + 1) * NT32) / MSPLIT;   // 78-79 tiles per split

    // Load all 16 B-fragments of tile t into register buffer BB (16 x dwordx4,
    // per-lane address = tile base + kk*1024 + lane*16; coalesced 1KB/fragment).
#define LOADB(BB, t)                                                               \
    do {                                                                           \
        const char* srcT_ = (const char*)Mb2 + (size_t)(t) * 16384 + l16;          \
        _Pragma("unroll")                                                          \
        for (int kk = 0; kk < 16; ++kk)                                            \
            BB[kk] = *(const short8*)(srcT_ + kk * 1024);                          \
    } while (0)

#define MFMA_K(BB, CUR, KK)                                                        \
    {                                                                              \
        accL##CUR = __builtin_amdgcn_mfma_f32_32x32x16_bf16(BB[KK], al[KK], accL##CUR, 0, 0, 0); \
        accH##CUR = __builtin_amdgcn_mfma_f32_32x32x16_bf16(BB[KK], ah[KK], accH##CUR, 0, 0, 0); \
    }

#define SM_P0(P)                                                                   \
    nmL = fmaxf(vmax16(accL##P), m0); nmH = fmaxf(vmax16(accH##P), m1);            \
    q0 = q1 = q2 = q3 = 0.f; r0x = r1x = r2x = r3x = 0.f;

#define SM_P1(P)                                                                   \
    q0 += ex2(accL##P[0] - nmL); q1 += ex2(accL##P[1] - nmL);                      \
    q2 += ex2(accL##P[2] - nmL); q3 += ex2(accL##P[3] - nmL);                      \
    q0 += ex2(accL##P[4] - nmL); q1 += ex2(accL##P[5] - nmL);                      \
    q2 += ex2(accL##P[6] - nmL); q3 += ex2(accL##P[7] - nmL);

#define SM_P2(P)                                                                   \
    q0 += ex2(accL##P[8]  - nmL); q1 += ex2(accL##P[9]  - nmL);                    \
    q2 += ex2(accL##P[10] - nmL); q3 += ex2(accL##P[11] - nmL);                    \
    q0 += ex2(accL##P[12] - nmL); q1 += ex2(accL##P[13] - nmL);                    \
    q2 += ex2(accL##P[14] - nmL); q3 += ex2(accL##P[15] - nmL);                    \
    s0 = fmaf(s0, ex2(m0 - nmL), (q0 + q1) + (q2 + q3)); m0 = nmL;

#define SM_P3(P)                                                                   \
    r0x += ex2(accH##P[0]  - nmH); r1x += ex2(accH##P[1]  - nmH);                  \
    r2x += ex2(accH##P[2]  - nmH); r3x += ex2(accH##P[3]  - nmH);                  \
    r0x += ex2(accH##P[4]  - nmH); r1x += ex2(accH##P[5]  - nmH);                  \
    r2x += ex2(accH##P[6]  - nmH); r3x += ex2(accH##P[7]  - nmH);                  \
    r0x += ex2(accH##P[8]  - nmH); r1x += ex2(accH##P[9]  - nmH);                  \
    r2x += ex2(accH##P[10] - nmH); r3x += ex2(accH##P[11] - nmH);                  \
    r0x += ex2(accH##P[12] - nmH); r1x += ex2(accH##P[13] - nmH);                  \
    r2x += ex2(accH##P[14] - nmH); r3x += ex2(accH##P[15] - nmH);                  \
    s1 = fmaf(s1, ex2(m1 - nmH), (r0x + r1x) + (r2x + r3x)); m1 = nmH;

    // MFMA(tile in BB -> CUR) with SM(prev tile PRV) interleaved in 4 chunks.
#define PIPE(BB, CUR, PRV)                                                         \
    do {                                                                           \
        f32x16 z_ = {0,0,0,0,0,0,0,0,0,0,0,0,0,0,0,0};                             \
        accL##CUR = z_; accH##CUR = z_;                                            \
        _Pragma("unroll") for (int kk = 0;  kk < 4;  ++kk) MFMA_K(BB, CUR, kk)     \
        SM_P0(PRV)                                                                 \
        _Pragma("unroll") for (int kk = 4;  kk < 8;  ++kk) MFMA_K(BB, CUR, kk)     \
        SM_P1(PRV)                                                                 \
        _Pragma("unroll") for (int kk = 8;  kk < 12; ++kk) MFMA_K(BB, CUR, kk)     \
        SM_P2(PRV)                                                                 \
        _Pragma("unroll") for (int kk = 12; kk < 16; ++kk) MFMA_K(BB, CUR, kk)     \
        SM_P3(PRV)                                                                 \
    } while (0)

#define MFMA_ONLY(BB, CUR)                                                         \
    do {                                                                           \
        f32x16 z_ = {0,0,0,0,0,0,0,0,0,0,0,0,0,0,0,0};                             \
        accL##CUR = z_; accH##CUR = z_;                                            \
        _Pragma("unroll") for (int kk = 0; kk < 16; ++kk) MFMA_K(BB, CUR, kk)      \
    } while (0)

#define SM_FULL(P) do { SM_P0(P) SM_P1(P) SM_P2(P) SM_P3(P) } while (0)

    // Prologue: fill both B buffers, compute tile t0 -> accA.
    LOADB(b0, t0);
    LOADB(b1, t0 + 1);         // nt >= 78, always exists
    MFMA_ONLY(b0, A);

    int t = t0 + 1;            // tile t is in b1 at loop head
    while (t + 1 < t1) {
        LOADB(b0, t + 1);      // prefetch next tile into the freed buffer
        PIPE(b1, B, A);        // tile t -> accB; softmax(tile t-1 = accA)
        if (t + 2 < t1) LOADB(b1, t + 2);
        PIPE(b0, A, B);        // tile t+1 -> accA; softmax(tile t = accB)
        t += 2;
    }
    if (t < t1) {              // one tile left, resident in b1
        PIPE(b1, B, A);
        SM_FULL(B);
    } else {
        SM_FULL(A);
    }

#undef SM_FULL
#undef MFMA_ONLY
#undef PIPE
#undef SM_P3
#undef SM_P2
#undef SM_P1
#undef SM_P0
#undef MFMA_K
#undef LOADB

    // Combine the two k-slice halves: lane l and l^32 hold the same row's two
    // 16-col subsets (for both row-halves).
    {
        float om = __shfl_xor(m0, 32, 64);
        float os = __shfl_xor(s0, 32, 64);
        float nm = fmaxf(m0, om);
        float sf = fmaf(s0, ex2(m0 - nm), os * ex2(om - nm));
        if (lane < 32) {
            pm[split * NROWS + rowbase + lane] = nm;
            ps[split * NROWS + rowbase + lane] = sf;
        }
    }
    {
        float om = __shfl_xor(m1, 32, 64);
        float os = __shfl_xor(s1, 32, 64);
        float nm = fmaxf(m1, om);
        float sf = fmaf(s1, ex2(m1 - nm), os * ex2(om - nm));
        if (lane < 32) {
            pm[split * NROWS + rowbase + 32 + lane] = nm;
            ps[split * NROWS + rowbase + 32 + lane] = sf;
        }
    }
}

__global__ void finalize_kernel(const int* __restrict__ gt, const float* __restrict__ wsel,
                                const float* __restrict__ pm, const float* __restrict__ ps,
                                float* __restrict__ bpart) {
    int tid = threadIdx.x;
    int i = blockIdx.x * 256 + tid;
    float mv[MSPLIT];
    float M = -3.0e38f;
    #pragma unroll
    for (int k = 0; k < MSPLIT; ++k) { mv[k] = pm[k * NROWS + i]; M = fmaxf(M, mv[k]); }
    float S = 0.0f;
    #pragma unroll
    for (int k = 0; k < MSPLIT; ++k) S += ps[k * NROWS + i] * ex2(mv[k] - M);
    float lse = (M + __log2f(S)) * LN2;   // back to natural-log domain
    int label = gt[i];
    float per = (label >= 0 && label < NCLS) ? (lse - wsel[i] * (1.0f / 6.0f)) : 0.0f;
    #pragma unroll
    for (int off = 32; off >= 1; off >>= 1) per += __shfl_xor(per, off, 64);
    __shared__ float red[4];
    int lane = tid & 63, wid = tid >> 6;
    if (lane == 0) red[wid] = per;
    __syncthreads();
    if (tid == 0) bpart[blockIdx.x] = red[0] + red[1] + red[2] + red[3];
}

__global__ void sum_kernel(const float* __restrict__ bpart, float* __restrict__ out) {
    int tid = threadIdx.x;
    float v = (tid < 32) ? bpart[tid] : 0.0f;
    #pragma unroll
    for (int off = 32; off >= 1; off >>= 1) v += __shfl_xor(v, off, 64);
    if (tid == 0) out[0] = 0.001f * v;
}

extern "C" void kernel_launch(void* const* d_in, const int* in_sizes, int n_in,
                              void* d_out, int out_size, void* d_ws, size_t ws_size,
                              hipStream_t stream) {
    const int*   gt    = (const int*)d_in[0];
    const float* F     = (const float*)d_in[1];
    const float* Mem   = (const float*)d_in[2];
    const int*   trace = (const int*)d_in[3];
    float* out = (float*)d_out;

    char* w = (char*)d_ws;
    unsigned short* Mb2 = (unsigned short*)w;
    unsigned short* Fb  = (unsigned short*)(w + 10240000);
    float* wsel  = (float*)(w + 14434304);
    float* pm    = (float*)(w + 14467072);
    float* ps    = (float*)(w + 14991360);
    float* bpart = (float*)(w + 15515648);

    prep_kernel<<<dim3(6596), dim3(256), 0, stream>>>(Mem, Mb2, F, Fb, gt, trace, wsel);
    lse_gemm<<<dim3(MSPLIT, NROWS / 256), dim3(256), 0, stream>>>(Fb, Mb2, pm, ps);
    finalize_kernel<<<dim3(NROWS / 256), dim3(256), 0, stream>>>(gt, wsel, pm, ps, bpart);
    sum_kernel<<<dim3(1), dim3(64), 0, stream>>>(bpart, out);
}